// Round 3
// baseline (1015.371 us; speedup 1.0000x reference)
//
#include <hip/hip_runtime.h>

#define NN 50000
#define NE 800000
#define HD 128

typedef short short8 __attribute__((ext_vector_type(8)));
typedef float floatx4 __attribute__((ext_vector_type(4)));
typedef unsigned short ushort4v __attribute__((ext_vector_type(4)));

static __device__ __forceinline__ unsigned short f2bf(float f) {
    unsigned int u = __float_as_uint(f);
    unsigned int lsb = (u >> 16) & 1u;
    u += 0x7fffu + lsb;
    return (unsigned short)(u >> 16);
}

static __device__ __forceinline__ floatx4 mfma16x16x32(short8 a, short8 b, floatx4 c) {
    asm("v_mfma_f32_16x16x32_bf16 %0, %1, %2, %0" : "+v"(c) : "v"(a), "v"(b));
    return c;
}

// Hazard guards: inline-asm MFMA is invisible to LLVM's GCNHazardRecognizer.
#define NOPGUARD_INIT8(A) asm volatile("s_nop 3" \
  : "+v"(A[0]),"+v"(A[1]),"+v"(A[2]),"+v"(A[3]),"+v"(A[4]),"+v"(A[5]),"+v"(A[6]),"+v"(A[7]))
#define NOPGUARD8(A) asm volatile("s_nop 7\ns_nop 7" \
  : "+v"(A[0]),"+v"(A[1]),"+v"(A[2]),"+v"(A[3]),"+v"(A[4]),"+v"(A[5]),"+v"(A[6]),"+v"(A[7]))

// ---------------- weight packing (unchanged) ----------------
__global__ void pack_weights(const float* __restrict__ mW1, const float* __restrict__ mW2,
                             const float* __restrict__ uW1, const float* __restrict__ uW2,
                             unsigned short* __restrict__ W1p, unsigned short* __restrict__ W2p,
                             unsigned short* __restrict__ U1p, unsigned short* __restrict__ U2p) {
    int t = blockIdx.x * 256 + threadIdx.x;
    const float* src; unsigned short* dst; int kmax; int i;
    if (t < 40960)        { src = mW1; dst = W1p; kmax = 291; i = t; }
    else if (t < 57344)   { src = mW2; dst = W2p; kmax = 128; i = t - 40960; }
    else if (t < 90112)   { src = uW1; dst = U1p; kmax = 256; i = t - 57344; }
    else if (t < 106496)  { src = uW2; dst = U2p; kmax = 128; i = t - 90112; }
    else return;
    int j = i & 7;
    int lane = (i >> 3) & 63;
    int n = (i >> 9) & 7;
    int kk = i >> 12;
    int k = kk * 32 + ((lane >> 4) << 3) + j;
    int c = n * 16 + (lane & 15);
    float v = (k < kmax) ? src[k * 128 + c] : 0.0f;
    dst[i] = f2bf(v);
}

// ---------------- CSR build: hist -> scan -> scatter ----------------
__global__ void hist_kernel(const int* __restrict__ ei, int* __restrict__ counts) {
    int e = blockIdx.x * 256 + threadIdx.x;
    if (e < NE) atomicAdd(&counts[ei[NE + e]], 1);
}

__global__ __launch_bounds__(1024)
void scan1_kernel(const int* __restrict__ counts, int* __restrict__ partial,
                  int* __restrict__ bsum) {
    __shared__ int wsum[16];
    int tid = threadIdx.x;
    int gid = blockIdx.x * 1024 + tid;
    int lane = tid & 63, w = tid >> 6;
    int v = (gid < NN) ? counts[gid] : 0;
    int s = v;
    #pragma unroll
    for (int o = 1; o < 64; o <<= 1) { int t = __shfl_up(s, o); if (lane >= o) s += t; }
    if (lane == 63) wsum[w] = s;
    __syncthreads();
    if (w == 0 && lane < 16) {
        int t = wsum[lane];
        #pragma unroll
        for (int o = 1; o < 16; o <<= 1) { int u = __shfl_up(t, o); if (lane >= o) t += u; }
        wsum[lane] = t;
    }
    __syncthreads();
    int base = (w > 0) ? wsum[w - 1] : 0;
    if (gid < NN) partial[gid] = base + s - v;   // exclusive within block
    if (tid == 1023) bsum[blockIdx.x] = base + s;
}

__global__ void scan2_kernel(int* __restrict__ bsum, int n) {
    int lane = threadIdx.x;
    int v = (lane < n) ? bsum[lane] : 0;
    int s = v;
    #pragma unroll
    for (int o = 1; o < 64; o <<= 1) { int t = __shfl_up(s, o); if (lane >= o) s += t; }
    if (lane < n) bsum[lane] = s - v;            // exclusive across blocks
}

__global__ void scatter_kernel(const int* __restrict__ ei, const int* __restrict__ partial,
                               const int* __restrict__ bsum, int* __restrict__ cursor,
                               int* __restrict__ eperm) {
    int e = blockIdx.x * 256 + threadIdx.x;
    if (e < NE) {
        int d = ei[NE + e];
        int pos = partial[d] + bsum[d >> 10] + atomicAdd(&cursor[d], 1);
        eperm[pos] = e;
    }
}

// ---------------- message MLP + segmented aggregation ----------------
// 64 dst-sorted edges per block; per-block segmented reduce, ~1 atomic row per
// distinct dst per block instead of one per edge.
__global__ __launch_bounds__(256, 2)
void msg_kernel(const float* __restrict__ x, const int* __restrict__ ei,
                const float* __restrict__ ea, const float* __restrict__ cd,
                const int* __restrict__ eperm,
                const unsigned short* __restrict__ W1p, const float* __restrict__ mb1,
                const unsigned short* __restrict__ W2p, const float* __restrict__ mb2,
                float* __restrict__ aggr) {
    __shared__ union {
        unsigned short sA[64 * 328];   // 64 edges x 320 feats (stride 328), layer-1 input
        float sOut[64 * 132];          // 64 x 128 fp32 outputs (stride 132), post layer-2
    } u;
    __shared__ unsigned short sH[64 * 136];
    __shared__ int sSrc[64];
    __shared__ int sDst[64];
    __shared__ int sEid[64];

    const int tid = threadIdx.x;
    const int e0 = blockIdx.x * 64;

    if (tid < 64) {
        int eid = eperm[e0 + tid];
        sEid[tid] = eid;
        sSrc[tid] = ei[eid];
        sDst[tid] = ei[NE + eid];
    }
    __syncthreads();

    // Stage msg_input tile: [x_src(128) | x_dst(128) | edge_attr(32) | rel(3)+pad]
    #pragma unroll
    for (int it = 0; it < 20; ++it) {
        int idx = it * 256 + tid;        // 80 float4-chunks per edge
        int e = idx / 80;
        int c = idx - e * 80;
        int f = c * 4;
        float4 v;
        if (f < 128) {
            v = *reinterpret_cast<const float4*>(x + sSrc[e] * 128 + f);
        } else if (f < 256) {
            v = *reinterpret_cast<const float4*>(x + sDst[e] * 128 + (f - 128));
        } else if (f < 288) {
            v = *reinterpret_cast<const float4*>(ea + sEid[e] * 32 + (f - 256));
        } else if (f == 288) {
            int s = sSrc[e], d = sDst[e];
            v.x = cd[d * 3 + 0] - cd[s * 3 + 0];
            v.y = cd[d * 3 + 1] - cd[s * 3 + 1];
            v.z = cd[d * 3 + 2] - cd[s * 3 + 2];
            v.w = 0.0f;
        } else {
            v.x = v.y = v.z = v.w = 0.0f;
        }
        ushort4v w = { f2bf(v.x), f2bf(v.y), f2bf(v.z), f2bf(v.w) };
        *reinterpret_cast<ushort4v*>(&u.sA[e * 328 + f]) = w;
    }
    __syncthreads();

    const int lane = tid & 63;
    const int wid = tid >> 6;
    const int g = lane >> 4;
    const int lr = lane & 15;
    const int arow = wid * 16 + lr;

    // Layer 1: (64x320) @ (320x128)
    floatx4 acc[8];
    #pragma unroll
    for (int n = 0; n < 8; ++n)
        #pragma unroll
        for (int r = 0; r < 4; ++r) acc[n][r] = 0.0f;
    NOPGUARD_INIT8(acc);

    #pragma unroll
    for (int kk = 0; kk < 10; ++kk) {
        short8 a = *reinterpret_cast<const short8*>(&u.sA[arow * 328 + kk * 32 + g * 8]);
        const short8* wb = reinterpret_cast<const short8*>(W1p) + (kk * 8) * 64 + lane;
        #pragma unroll
        for (int n = 0; n < 8; ++n) {
            short8 b = wb[n * 64];
            acc[n] = mfma16x16x32(a, b, acc[n]);
        }
    }
    NOPGUARD8(acc);

    // bias + ReLU -> sH (bf16)
    #pragma unroll
    for (int n = 0; n < 8; ++n) {
        float bias = mb1[n * 16 + lr];
        #pragma unroll
        for (int r = 0; r < 4; ++r) {
            int row = wid * 16 + g * 4 + r;
            float v = acc[n][r] + bias;
            v = fmaxf(v, 0.0f);
            sH[row * 136 + n * 16 + lr] = f2bf(v);
        }
    }
    __syncthreads();   // also guarantees all u.sA reads are complete

    // Layer 2: (64x128) @ (128x128)
    floatx4 acc2[8];
    #pragma unroll
    for (int n = 0; n < 8; ++n)
        #pragma unroll
        for (int r = 0; r < 4; ++r) acc2[n][r] = 0.0f;
    NOPGUARD_INIT8(acc2);

    #pragma unroll
    for (int kk = 0; kk < 4; ++kk) {
        short8 a = *reinterpret_cast<const short8*>(&sH[arow * 136 + kk * 32 + g * 8]);
        const short8* wb = reinterpret_cast<const short8*>(W2p) + (kk * 8) * 64 + lane;
        #pragma unroll
        for (int n = 0; n < 8; ++n) {
            short8 b = wb[n * 64];
            acc2[n] = mfma16x16x32(a, b, acc2[n]);
        }
    }
    NOPGUARD8(acc2);

    // bias -> fp32 LDS tile (overlays sA; all sA reads done at the sync above)
    #pragma unroll
    for (int n = 0; n < 8; ++n) {
        float bias = mb2[n * 16 + lr];
        #pragma unroll
        for (int r = 0; r < 4; ++r) {
            int row = wid * 16 + g * 4 + r;
            u.sOut[row * 132 + n * 16 + lr] = acc2[n][r] + bias;
        }
    }
    __syncthreads();

    // Segmented reduction over dst-sorted rows: one atomic row per distinct dst.
    {
        int col = tid & 127;
        int half = tid >> 7;
        int row = 0, s = 0;
        while (row < 64) {
            int d = sDst[row];
            int row2 = row + 1;
            while (row2 < 64 && sDst[row2] == d) ++row2;
            if ((s & 1) == half) {
                float sum = 0.0f;
                for (int r = row; r < row2; ++r) sum += u.sOut[r * 132 + col];
                atomicAdd(&aggr[d * 128 + col], sum);
            }
            row = row2; ++s;
        }
    }
}

// ---------------- node update MLP + residual + LayerNorm (unchanged) ----------------
__global__ __launch_bounds__(256, 2)
void node_kernel(const float* __restrict__ x, const float* __restrict__ aggr,
                 const unsigned short* __restrict__ U1p, const float* __restrict__ ub1,
                 const unsigned short* __restrict__ U2p, const float* __restrict__ ub2,
                 const float* __restrict__ gamma, const float* __restrict__ beta,
                 float* __restrict__ out) {
    __shared__ unsigned short sA[64 * 264];
    __shared__ unsigned short sH[64 * 136];

    const int tid = threadIdx.x;
    const int n0 = blockIdx.x * 64;

    #pragma unroll
    for (int it = 0; it < 16; ++it) {
        int idx = it * 256 + tid;
        int e = idx >> 6;
        int f = (idx & 63) * 4;
        int nd = n0 + e;
        if (nd >= NN) nd = NN - 1;
        float4 v;
        if (f < 128) v = *reinterpret_cast<const float4*>(x + nd * 128 + f);
        else         v = *reinterpret_cast<const float4*>(aggr + nd * 128 + (f - 128));
        ushort4v w = { f2bf(v.x), f2bf(v.y), f2bf(v.z), f2bf(v.w) };
        *reinterpret_cast<ushort4v*>(&sA[e * 264 + f]) = w;
    }
    __syncthreads();

    const int lane = tid & 63;
    const int wid = tid >> 6;
    const int g = lane >> 4;
    const int lr = lane & 15;
    const int arow = wid * 16 + lr;

    floatx4 acc[8];
    #pragma unroll
    for (int n = 0; n < 8; ++n)
        #pragma unroll
        for (int r = 0; r < 4; ++r) acc[n][r] = 0.0f;
    NOPGUARD_INIT8(acc);

    #pragma unroll
    for (int kk = 0; kk < 8; ++kk) {
        short8 a = *reinterpret_cast<const short8*>(&sA[arow * 264 + kk * 32 + g * 8]);
        const short8* wb = reinterpret_cast<const short8*>(U1p) + (kk * 8) * 64 + lane;
        #pragma unroll
        for (int n = 0; n < 8; ++n) {
            short8 b = wb[n * 64];
            acc[n] = mfma16x16x32(a, b, acc[n]);
        }
    }
    NOPGUARD8(acc);

    #pragma unroll
    for (int n = 0; n < 8; ++n) {
        float bias = ub1[n * 16 + lr];
        #pragma unroll
        for (int r = 0; r < 4; ++r) {
            int row = wid * 16 + g * 4 + r;
            float v = acc[n][r] + bias;
            v = fmaxf(v, 0.0f);
            sH[row * 136 + n * 16 + lr] = f2bf(v);
        }
    }
    __syncthreads();

    floatx4 acc2[8];
    #pragma unroll
    for (int n = 0; n < 8; ++n)
        #pragma unroll
        for (int r = 0; r < 4; ++r) acc2[n][r] = 0.0f;
    NOPGUARD_INIT8(acc2);

    #pragma unroll
    for (int kk = 0; kk < 4; ++kk) {
        short8 a = *reinterpret_cast<const short8*>(&sH[arow * 136 + kk * 32 + g * 8]);
        const short8* wb = reinterpret_cast<const short8*>(U2p) + (kk * 8) * 64 + lane;
        #pragma unroll
        for (int n = 0; n < 8; ++n) {
            short8 b = wb[n * 64];
            acc2[n] = mfma16x16x32(a, b, acc2[n]);
        }
    }
    NOPGUARD8(acc2);

    #pragma unroll
    for (int r = 0; r < 4; ++r) {
        int row = wid * 16 + g * 4 + r;
        int nd = n0 + row;
        int ndc = (nd < NN) ? nd : (NN - 1);
        float vals[8];
        float s1 = 0.0f, s2 = 0.0f;
        #pragma unroll
        for (int n = 0; n < 8; ++n) {
            int col = n * 16 + lr;
            float v = acc2[n][r] + ub2[col] + x[ndc * 128 + col];
            vals[n] = v;
            s1 += v;
            s2 += v * v;
        }
        #pragma unroll
        for (int m = 1; m < 16; m <<= 1) {
            s1 += __shfl_xor(s1, m);
            s2 += __shfl_xor(s2, m);
        }
        float mean = s1 * (1.0f / 128.0f);
        float var = s2 * (1.0f / 128.0f) - mean * mean;
        float inv = rsqrtf(var + 1e-5f);
        if (nd < NN) {
            #pragma unroll
            for (int n = 0; n < 8; ++n) {
                int col = n * 16 + lr;
                out[nd * 128 + col] = (vals[n] - mean) * inv * gamma[col] + beta[col];
            }
        }
    }
}

extern "C" void kernel_launch(void* const* d_in, const int* in_sizes, int n_in,
                              void* d_out, int out_size, void* d_ws, size_t ws_size,
                              hipStream_t stream) {
    const float* x     = (const float*)d_in[0];
    const int*   ei    = (const int*)d_in[1];
    const float* ea    = (const float*)d_in[2];
    const float* cd    = (const float*)d_in[3];
    const float* mW1   = (const float*)d_in[4];
    const float* mb1   = (const float*)d_in[5];
    const float* mW2   = (const float*)d_in[6];
    const float* mb2   = (const float*)d_in[7];
    const float* uW1   = (const float*)d_in[8];
    const float* ub1   = (const float*)d_in[9];
    const float* uW2   = (const float*)d_in[10];
    const float* ub2   = (const float*)d_in[11];
    const float* gamma = (const float*)d_in[12];
    const float* beta  = (const float*)d_in[13];
    float* out = (float*)d_out;

    char* ws = (char*)d_ws;
    unsigned short* W1p = (unsigned short*)(ws);              // 81,920 B
    unsigned short* W2p = (unsigned short*)(ws + 81920);      // 32,768 B
    unsigned short* U1p = (unsigned short*)(ws + 114688);     // 65,536 B
    unsigned short* U2p = (unsigned short*)(ws + 180224);     // 32,768 B
    int* counts  = (int*)(ws + 212992);                       // 200,704 B
    int* partial = (int*)(ws + 413696);                       // 200,704 B
    int* bsum    = (int*)(ws + 614400);                       // 256 B
    int* cursor  = (int*)(ws + 614656);                       // 200,704 B
    int* eperm   = (int*)(ws + 815360);                       // 3,200,000 B

    float* aggr = out;   // aggr lives in d_out (exactly NN*HD floats)

    hipMemsetAsync(counts, 0, NN * sizeof(int), stream);
    hipMemsetAsync(cursor, 0, NN * sizeof(int), stream);
    hipMemsetAsync(aggr, 0, (size_t)NN * HD * sizeof(float), stream);

    pack_weights<<<416, 256, 0, stream>>>(mW1, mW2, uW1, uW2, W1p, W2p, U1p, U2p);
    hist_kernel<<<(NE + 255) / 256, 256, 0, stream>>>(ei, counts);
    scan1_kernel<<<(NN + 1023) / 1024, 1024, 0, stream>>>(counts, partial, bsum);
    scan2_kernel<<<1, 64, 0, stream>>>(bsum, (NN + 1023) / 1024);
    scatter_kernel<<<(NE + 255) / 256, 256, 0, stream>>>(ei, partial, bsum, cursor, eperm);
    msg_kernel<<<NE / 64, 256, 0, stream>>>(x, ei, ea, cd, eperm, W1p, mb1, W2p, mb2, aggr);
    node_kernel<<<(NN + 63) / 64, 256, 0, stream>>>(x, aggr, U1p, ub1, U2p, ub2, gamma, beta, out);
}

// Round 4
// 409.423 us; speedup vs baseline: 2.4800x; 2.4800x over previous
//
#include <hip/hip_runtime.h>

#define NN 50000
#define NE 800000
#define HD 128

typedef short short8 __attribute__((ext_vector_type(8)));
typedef float floatx4 __attribute__((ext_vector_type(4)));
typedef unsigned short ushort4v __attribute__((ext_vector_type(4)));

static __device__ __forceinline__ unsigned short f2bf(float f) {
    unsigned int u = __float_as_uint(f);
    unsigned int lsb = (u >> 16) & 1u;
    u += 0x7fffu + lsb;
    return (unsigned short)(u >> 16);
}

static __device__ __forceinline__ short8 pack2(float4 a, float4 b) {
    short8 r;
    r[0] = (short)f2bf(a.x); r[1] = (short)f2bf(a.y);
    r[2] = (short)f2bf(a.z); r[3] = (short)f2bf(a.w);
    r[4] = (short)f2bf(b.x); r[5] = (short)f2bf(b.y);
    r[6] = (short)f2bf(b.z); r[7] = (short)f2bf(b.w);
    return r;
}

static __device__ __forceinline__ floatx4 mfma16x16x32(short8 a, short8 b, floatx4 c) {
    asm("v_mfma_f32_16x16x32_bf16 %0, %1, %2, %0" : "+v"(c) : "v"(a), "v"(b));
    return c;
}

// Hazard guards: inline-asm MFMA is invisible to LLVM's GCNHazardRecognizer.
#define NOPGUARD_INIT8(A) asm volatile("s_nop 3" \
  : "+v"(A[0]),"+v"(A[1]),"+v"(A[2]),"+v"(A[3]),"+v"(A[4]),"+v"(A[5]),"+v"(A[6]),"+v"(A[7]))
#define NOPGUARD8(A) asm volatile("s_nop 7\ns_nop 7" \
  : "+v"(A[0]),"+v"(A[1]),"+v"(A[2]),"+v"(A[3]),"+v"(A[4]),"+v"(A[5]),"+v"(A[6]),"+v"(A[7]))

// ---------------- weight packing (unchanged) ----------------
__global__ void pack_weights(const float* __restrict__ mW1, const float* __restrict__ mW2,
                             const float* __restrict__ uW1, const float* __restrict__ uW2,
                             unsigned short* __restrict__ W1p, unsigned short* __restrict__ W2p,
                             unsigned short* __restrict__ U1p, unsigned short* __restrict__ U2p) {
    int t = blockIdx.x * 256 + threadIdx.x;
    const float* src; unsigned short* dst; int kmax; int i;
    if (t < 40960)        { src = mW1; dst = W1p; kmax = 291; i = t; }
    else if (t < 57344)   { src = mW2; dst = W2p; kmax = 128; i = t - 40960; }
    else if (t < 90112)   { src = uW1; dst = U1p; kmax = 256; i = t - 57344; }
    else if (t < 106496)  { src = uW2; dst = U2p; kmax = 128; i = t - 90112; }
    else return;
    int j = i & 7;
    int lane = (i >> 3) & 63;
    int n = (i >> 9) & 7;
    int kk = i >> 12;
    int k = kk * 32 + ((lane >> 4) << 3) + j;
    int c = n * 16 + (lane & 15);
    float v = (k < kmax) ? src[k * 128 + c] : 0.0f;
    dst[i] = f2bf(v);
}

// ---------------- CSR build: hist -> scan -> scatter (unchanged) ----------------
__global__ void hist_kernel(const int* __restrict__ ei, int* __restrict__ counts) {
    int e = blockIdx.x * 256 + threadIdx.x;
    if (e < NE) atomicAdd(&counts[ei[NE + e]], 1);
}

__global__ __launch_bounds__(1024)
void scan1_kernel(const int* __restrict__ counts, int* __restrict__ partial,
                  int* __restrict__ bsum) {
    __shared__ int wsum[16];
    int tid = threadIdx.x;
    int gid = blockIdx.x * 1024 + tid;
    int lane = tid & 63, w = tid >> 6;
    int v = (gid < NN) ? counts[gid] : 0;
    int s = v;
    #pragma unroll
    for (int o = 1; o < 64; o <<= 1) { int t = __shfl_up(s, o); if (lane >= o) s += t; }
    if (lane == 63) wsum[w] = s;
    __syncthreads();
    if (w == 0 && lane < 16) {
        int t = wsum[lane];
        #pragma unroll
        for (int o = 1; o < 16; o <<= 1) { int u = __shfl_up(t, o); if (lane >= o) t += u; }
        wsum[lane] = t;
    }
    __syncthreads();
    int base = (w > 0) ? wsum[w - 1] : 0;
    if (gid < NN) partial[gid] = base + s - v;
    if (tid == 1023) bsum[blockIdx.x] = base + s;
}

__global__ void scan2_kernel(int* __restrict__ bsum, int n) {
    int lane = threadIdx.x;
    int v = (lane < n) ? bsum[lane] : 0;
    int s = v;
    #pragma unroll
    for (int o = 1; o < 64; o <<= 1) { int t = __shfl_up(s, o); if (lane >= o) s += t; }
    if (lane < n) bsum[lane] = s - v;
}

__global__ void scatter_kernel(const int* __restrict__ ei, const int* __restrict__ partial,
                               const int* __restrict__ bsum, int* __restrict__ cursor,
                               int* __restrict__ eperm) {
    int e = blockIdx.x * 256 + threadIdx.x;
    if (e < NE) {
        int d = ei[NE + e];
        int pos = partial[d] + bsum[d >> 10] + atomicAdd(&cursor[d], 1);
        eperm[pos] = e;
    }
}

// ---------------- message MLP: lane-direct gather + segmented aggregation ----------------
// 64 dst-sorted edges per block, 4 waves. Each lane gathers its A-fragments
// directly from global (18 independent float4 loads) -- no staged LDS tile,
// no divergent staging loop.
__global__ __launch_bounds__(256, 4)
void msg_kernel(const float* __restrict__ x, const int* __restrict__ ei,
                const float* __restrict__ ea, const float* __restrict__ cd,
                const int* __restrict__ eperm,
                const unsigned short* __restrict__ W1p, const float* __restrict__ mb1,
                const unsigned short* __restrict__ W2p, const float* __restrict__ mb2,
                float* __restrict__ aggr) {
    __shared__ union {
        unsigned short sH[64 * 136];   // bf16 hidden tile (layer-1 out), stride 136
        float sOut[64 * 132];          // fp32 outputs (layer-2 out), stride 132
    } u;
    __shared__ int sDst[64];

    const int tid = threadIdx.x;
    const int lane = tid & 63;
    const int wid = tid >> 6;
    const int g = lane >> 4;
    const int lr = lane & 15;
    const int arow = wid * 16 + lr;          // this lane's edge row in the 64-tile
    const int e0 = blockIdx.x * 64;

    const int eid = eperm[e0 + arow];
    const int src = ei[eid];
    const int dst = ei[NE + eid];
    if (g == 0) sDst[arow] = dst;

    // 18 independent gathers straight into fragment slices.
    const float* xs = x + (size_t)src * 128 + g * 8;
    const float* xd = x + (size_t)dst * 128 + g * 8;
    const float* ep = ea + (size_t)eid * 32 + g * 8;
    float4 ts[8], td[8], te[2];
    #pragma unroll
    for (int kk = 0; kk < 4; ++kk) {
        ts[2 * kk]     = *reinterpret_cast<const float4*>(xs + kk * 32);
        ts[2 * kk + 1] = *reinterpret_cast<const float4*>(xs + kk * 32 + 4);
        td[2 * kk]     = *reinterpret_cast<const float4*>(xd + kk * 32);
        td[2 * kk + 1] = *reinterpret_cast<const float4*>(xd + kk * 32 + 4);
    }
    te[0] = *reinterpret_cast<const float4*>(ep);
    te[1] = *reinterpret_cast<const float4*>(ep + 4);
    float rel0 = 0.0f, rel1 = 0.0f, rel2 = 0.0f;
    if (g == 0) {
        rel0 = cd[dst * 3 + 0] - cd[src * 3 + 0];
        rel1 = cd[dst * 3 + 1] - cd[src * 3 + 1];
        rel2 = cd[dst * 3 + 2] - cd[src * 3 + 2];
    }

    short8 af[10];
    #pragma unroll
    for (int kk = 0; kk < 4; ++kk) {
        af[kk]     = pack2(ts[2 * kk], ts[2 * kk + 1]);
        af[4 + kk] = pack2(td[2 * kk], td[2 * kk + 1]);
    }
    af[8] = pack2(te[0], te[1]);
    {   // k 288..319: rel for g==0 j<3; zeros elsewhere (k>=291 weights are zero-padded)
        float4 r0; r0.x = rel0; r0.y = rel1; r0.z = rel2; r0.w = 0.0f;
        float4 r1; r1.x = 0.0f; r1.y = 0.0f; r1.z = 0.0f; r1.w = 0.0f;
        af[9] = pack2(r0, r1);
    }

    // Layer 1: (64x320) @ (320x128)
    floatx4 acc[8];
    #pragma unroll
    for (int n = 0; n < 8; ++n)
        #pragma unroll
        for (int r = 0; r < 4; ++r) acc[n][r] = 0.0f;
    NOPGUARD_INIT8(acc);

    #pragma unroll
    for (int kk = 0; kk < 10; ++kk) {
        const short8* wb = reinterpret_cast<const short8*>(W1p) + (kk * 8) * 64 + lane;
        #pragma unroll
        for (int n = 0; n < 8; ++n)
            acc[n] = mfma16x16x32(af[kk], wb[n * 64], acc[n]);
    }
    NOPGUARD8(acc);

    // bias + ReLU -> sH (bf16)
    #pragma unroll
    for (int n = 0; n < 8; ++n) {
        float bias = mb1[n * 16 + lr];
        #pragma unroll
        for (int r = 0; r < 4; ++r) {
            int row = wid * 16 + g * 4 + r;
            u.sH[row * 136 + n * 16 + lr] = f2bf(fmaxf(acc[n][r] + bias, 0.0f));
        }
    }
    __syncthreads();

    // Pull layer-2 A fragments to registers, then free the union for sOut.
    short8 a2[4];
    #pragma unroll
    for (int kk = 0; kk < 4; ++kk)
        a2[kk] = *reinterpret_cast<const short8*>(&u.sH[arow * 136 + kk * 32 + g * 8]);
    __syncthreads();

    // Layer 2: (64x128) @ (128x128)
    floatx4 acc2[8];
    #pragma unroll
    for (int n = 0; n < 8; ++n)
        #pragma unroll
        for (int r = 0; r < 4; ++r) acc2[n][r] = 0.0f;
    NOPGUARD_INIT8(acc2);

    #pragma unroll
    for (int kk = 0; kk < 4; ++kk) {
        const short8* wb = reinterpret_cast<const short8*>(W2p) + (kk * 8) * 64 + lane;
        #pragma unroll
        for (int n = 0; n < 8; ++n)
            acc2[n] = mfma16x16x32(a2[kk], wb[n * 64], acc2[n]);
    }
    NOPGUARD8(acc2);

    // bias -> fp32 LDS tile
    #pragma unroll
    for (int n = 0; n < 8; ++n) {
        float bias = mb2[n * 16 + lr];
        #pragma unroll
        for (int r = 0; r < 4; ++r) {
            int row = wid * 16 + g * 4 + r;
            u.sOut[row * 132 + n * 16 + lr] = acc2[n][r] + bias;
        }
    }
    __syncthreads();

    // Segmented reduction over dst-sorted rows: one atomic row per distinct dst.
    {
        int col = tid & 127;
        int half = tid >> 7;
        int row = 0, s = 0;
        while (row < 64) {
            int d = sDst[row];
            int row2 = row + 1;
            while (row2 < 64 && sDst[row2] == d) ++row2;
            if ((s & 1) == half) {
                float sum = 0.0f;
                for (int r = row; r < row2; ++r) sum += u.sOut[r * 132 + col];
                atomicAdd(&aggr[d * 128 + col], sum);
            }
            row = row2; ++s;
        }
    }
}

// ---------------- node update MLP + residual + LayerNorm (unchanged) ----------------
__global__ __launch_bounds__(256, 2)
void node_kernel(const float* __restrict__ x, const float* __restrict__ aggr,
                 const unsigned short* __restrict__ U1p, const float* __restrict__ ub1,
                 const unsigned short* __restrict__ U2p, const float* __restrict__ ub2,
                 const float* __restrict__ gamma, const float* __restrict__ beta,
                 float* __restrict__ out) {
    __shared__ unsigned short sA[64 * 264];
    __shared__ unsigned short sH[64 * 136];

    const int tid = threadIdx.x;
    const int n0 = blockIdx.x * 64;

    #pragma unroll
    for (int it = 0; it < 16; ++it) {
        int idx = it * 256 + tid;
        int e = idx >> 6;
        int f = (idx & 63) * 4;
        int nd = n0 + e;
        if (nd >= NN) nd = NN - 1;
        float4 v;
        if (f < 128) v = *reinterpret_cast<const float4*>(x + nd * 128 + f);
        else         v = *reinterpret_cast<const float4*>(aggr + nd * 128 + (f - 128));
        ushort4v w = { f2bf(v.x), f2bf(v.y), f2bf(v.z), f2bf(v.w) };
        *reinterpret_cast<ushort4v*>(&sA[e * 264 + f]) = w;
    }
    __syncthreads();

    const int lane = tid & 63;
    const int wid = tid >> 6;
    const int g = lane >> 4;
    const int lr = lane & 15;
    const int arow = wid * 16 + lr;

    floatx4 acc[8];
    #pragma unroll
    for (int n = 0; n < 8; ++n)
        #pragma unroll
        for (int r = 0; r < 4; ++r) acc[n][r] = 0.0f;
    NOPGUARD_INIT8(acc);

    #pragma unroll
    for (int kk = 0; kk < 8; ++kk) {
        short8 a = *reinterpret_cast<const short8*>(&sA[arow * 264 + kk * 32 + g * 8]);
        const short8* wb = reinterpret_cast<const short8*>(U1p) + (kk * 8) * 64 + lane;
        #pragma unroll
        for (int n = 0; n < 8; ++n) {
            short8 b = wb[n * 64];
            acc[n] = mfma16x16x32(a, b, acc[n]);
        }
    }
    NOPGUARD8(acc);

    #pragma unroll
    for (int n = 0; n < 8; ++n) {
        float bias = ub1[n * 16 + lr];
        #pragma unroll
        for (int r = 0; r < 4; ++r) {
            int row = wid * 16 + g * 4 + r;
            float v = acc[n][r] + bias;
            v = fmaxf(v, 0.0f);
            sH[row * 136 + n * 16 + lr] = f2bf(v);
        }
    }
    __syncthreads();

    floatx4 acc2[8];
    #pragma unroll
    for (int n = 0; n < 8; ++n)
        #pragma unroll
        for (int r = 0; r < 4; ++r) acc2[n][r] = 0.0f;
    NOPGUARD_INIT8(acc2);

    #pragma unroll
    for (int kk = 0; kk < 4; ++kk) {
        short8 a = *reinterpret_cast<const short8*>(&sH[arow * 136 + kk * 32 + g * 8]);
        const short8* wb = reinterpret_cast<const short8*>(U2p) + (kk * 8) * 64 + lane;
        #pragma unroll
        for (int n = 0; n < 8; ++n) {
            short8 b = wb[n * 64];
            acc2[n] = mfma16x16x32(a, b, acc2[n]);
        }
    }
    NOPGUARD8(acc2);

    #pragma unroll
    for (int r = 0; r < 4; ++r) {
        int row = wid * 16 + g * 4 + r;
        int nd = n0 + row;
        int ndc = (nd < NN) ? nd : (NN - 1);
        float vals[8];
        float s1 = 0.0f, s2 = 0.0f;
        #pragma unroll
        for (int n = 0; n < 8; ++n) {
            int col = n * 16 + lr;
            float v = acc2[n][r] + ub2[col] + x[ndc * 128 + col];
            vals[n] = v;
            s1 += v;
            s2 += v * v;
        }
        #pragma unroll
        for (int m = 1; m < 16; m <<= 1) {
            s1 += __shfl_xor(s1, m);
            s2 += __shfl_xor(s2, m);
        }
        float mean = s1 * (1.0f / 128.0f);
        float var = s2 * (1.0f / 128.0f) - mean * mean;
        float inv = rsqrtf(var + 1e-5f);
        if (nd < NN) {
            #pragma unroll
            for (int n = 0; n < 8; ++n) {
                int col = n * 16 + lr;
                out[nd * 128 + col] = (vals[n] - mean) * inv * gamma[col] + beta[col];
            }
        }
    }
}

extern "C" void kernel_launch(void* const* d_in, const int* in_sizes, int n_in,
                              void* d_out, int out_size, void* d_ws, size_t ws_size,
                              hipStream_t stream) {
    const float* x     = (const float*)d_in[0];
    const int*   ei    = (const int*)d_in[1];
    const float* ea    = (const float*)d_in[2];
    const float* cd    = (const float*)d_in[3];
    const float* mW1   = (const float*)d_in[4];
    const float* mb1   = (const float*)d_in[5];
    const float* mW2   = (const float*)d_in[6];
    const float* mb2   = (const float*)d_in[7];
    const float* uW1   = (const float*)d_in[8];
    const float* ub1   = (const float*)d_in[9];
    const float* uW2   = (const float*)d_in[10];
    const float* ub2   = (const float*)d_in[11];
    const float* gamma = (const float*)d_in[12];
    const float* beta  = (const float*)d_in[13];
    float* out = (float*)d_out;

    char* ws = (char*)d_ws;
    unsigned short* W1p = (unsigned short*)(ws);              // 81,920 B
    unsigned short* W2p = (unsigned short*)(ws + 81920);      // 32,768 B
    unsigned short* U1p = (unsigned short*)(ws + 114688);     // 65,536 B
    unsigned short* U2p = (unsigned short*)(ws + 180224);     // 32,768 B
    int* counts  = (int*)(ws + 212992);                       // 200,704 B
    int* partial = (int*)(ws + 413696);                       // 200,704 B
    int* bsum    = (int*)(ws + 614400);                       // 256 B
    int* cursor  = (int*)(ws + 614656);                       // 200,704 B
    int* eperm   = (int*)(ws + 815360);                       // 3,200,000 B

    float* aggr = out;   // aggr lives in d_out (exactly NN*HD floats)

    hipMemsetAsync(counts, 0, NN * sizeof(int), stream);
    hipMemsetAsync(cursor, 0, NN * sizeof(int), stream);
    hipMemsetAsync(aggr, 0, (size_t)NN * HD * sizeof(float), stream);

    pack_weights<<<416, 256, 0, stream>>>(mW1, mW2, uW1, uW2, W1p, W2p, U1p, U2p);
    hist_kernel<<<(NE + 255) / 256, 256, 0, stream>>>(ei, counts);
    scan1_kernel<<<(NN + 1023) / 1024, 1024, 0, stream>>>(counts, partial, bsum);
    scan2_kernel<<<1, 64, 0, stream>>>(bsum, (NN + 1023) / 1024);
    scatter_kernel<<<(NE + 255) / 256, 256, 0, stream>>>(ei, partial, bsum, cursor, eperm);
    msg_kernel<<<NE / 64, 256, 0, stream>>>(x, ei, ea, cd, eperm, W1p, mb1, W2p, mb2, aggr);
    node_kernel<<<(NN + 63) / 64, 256, 0, stream>>>(x, aggr, U1p, ub1, U2p, ub2, gamma, beta, out);
}

// Round 6
// 388.425 us; speedup vs baseline: 2.6141x; 1.0541x over previous
//
#include <hip/hip_runtime.h>

#define NN 50000
#define NE 800000
#define HD 128

typedef short short8 __attribute__((ext_vector_type(8)));
typedef float floatx4 __attribute__((ext_vector_type(4)));

static __device__ __forceinline__ unsigned short f2bf(float f) {
    unsigned int u = __float_as_uint(f);
    unsigned int lsb = (u >> 16) & 1u;
    u += 0x7fffu + lsb;
    return (unsigned short)(u >> 16);
}

// HW packed f32->bf16 (RNE), 2 elems/instr; lo=src0, hi=src1 (T12 verified order).
static __device__ __forceinline__ short8 pack2(float4 a, float4 b) {
    union { unsigned int u[4]; short8 s; } r;
    asm("v_cvt_pk_bf16_f32 %0, %1, %2" : "=v"(r.u[0]) : "v"(a.x), "v"(a.y));
    asm("v_cvt_pk_bf16_f32 %0, %1, %2" : "=v"(r.u[1]) : "v"(a.z), "v"(a.w));
    asm("v_cvt_pk_bf16_f32 %0, %1, %2" : "=v"(r.u[2]) : "v"(b.x), "v"(b.y));
    asm("v_cvt_pk_bf16_f32 %0, %1, %2" : "=v"(r.u[3]) : "v"(b.z), "v"(b.w));
    return r.s;
}

static __device__ __forceinline__ floatx4 mfma16x16x32(short8 a, short8 b, floatx4 c) {
    asm("v_mfma_f32_16x16x32_bf16 %0, %1, %2, %0" : "+v"(c) : "v"(a), "v"(b));
    return c;
}

// Hazard guards: inline-asm MFMA is invisible to LLVM's GCNHazardRecognizer.
#define NOPGUARD_INIT8(A) asm volatile("s_nop 3" \
  : "+v"(A[0]),"+v"(A[1]),"+v"(A[2]),"+v"(A[3]),"+v"(A[4]),"+v"(A[5]),"+v"(A[6]),"+v"(A[7]))
#define NOPGUARD8(A) asm volatile("s_nop 7\ns_nop 7" \
  : "+v"(A[0]),"+v"(A[1]),"+v"(A[2]),"+v"(A[3]),"+v"(A[4]),"+v"(A[5]),"+v"(A[6]),"+v"(A[7]))

// ---------------- weight packing (unchanged) ----------------
__global__ void pack_weights(const float* __restrict__ mW1, const float* __restrict__ mW2,
                             const float* __restrict__ uW1, const float* __restrict__ uW2,
                             unsigned short* __restrict__ W1p, unsigned short* __restrict__ W2p,
                             unsigned short* __restrict__ U1p, unsigned short* __restrict__ U2p) {
    int t = blockIdx.x * 256 + threadIdx.x;
    const float* src; unsigned short* dst; int kmax; int i;
    if (t < 40960)        { src = mW1; dst = W1p; kmax = 291; i = t; }
    else if (t < 57344)   { src = mW2; dst = W2p; kmax = 128; i = t - 40960; }
    else if (t < 90112)   { src = uW1; dst = U1p; kmax = 256; i = t - 57344; }
    else if (t < 106496)  { src = uW2; dst = U2p; kmax = 128; i = t - 90112; }
    else return;
    int j = i & 7;
    int lane = (i >> 3) & 63;
    int n = (i >> 9) & 7;
    int kk = i >> 12;
    int k = kk * 32 + ((lane >> 4) << 3) + j;
    int c = n * 16 + (lane & 15);
    float v = (k < kmax) ? src[k * 128 + c] : 0.0f;
    dst[i] = f2bf(v);
}

// ---------------- CSR build: hist -> scan -> scatter (unchanged) ----------------
__global__ void hist_kernel(const int* __restrict__ ei, int* __restrict__ counts) {
    int e = blockIdx.x * 256 + threadIdx.x;
    if (e < NE) atomicAdd(&counts[ei[NE + e]], 1);
}

__global__ __launch_bounds__(1024)
void scan1_kernel(const int* __restrict__ counts, int* __restrict__ partial,
                  int* __restrict__ bsum) {
    __shared__ int wsum[16];
    int tid = threadIdx.x;
    int gid = blockIdx.x * 1024 + tid;
    int lane = tid & 63, w = tid >> 6;
    int v = (gid < NN) ? counts[gid] : 0;
    int s = v;
    #pragma unroll
    for (int o = 1; o < 64; o <<= 1) { int t = __shfl_up(s, o); if (lane >= o) s += t; }
    if (lane == 63) wsum[w] = s;
    __syncthreads();
    if (w == 0 && lane < 16) {
        int t = wsum[lane];
        #pragma unroll
        for (int o = 1; o < 16; o <<= 1) { int u = __shfl_up(t, o); if (lane >= o) t += u; }
        wsum[lane] = t;
    }
    __syncthreads();
    int base = (w > 0) ? wsum[w - 1] : 0;
    if (gid < NN) partial[gid] = base + s - v;
    if (tid == 1023) bsum[blockIdx.x] = base + s;
}

__global__ void scan2_kernel(int* __restrict__ bsum, int n) {
    int lane = threadIdx.x;
    int v = (lane < n) ? bsum[lane] : 0;
    int s = v;
    #pragma unroll
    for (int o = 1; o < 64; o <<= 1) { int t = __shfl_up(s, o); if (lane >= o) s += t; }
    if (lane < n) bsum[lane] = s - v;
}

__global__ void scatter_kernel(const int* __restrict__ ei, const int* __restrict__ partial,
                               const int* __restrict__ bsum, int* __restrict__ cursor,
                               int* __restrict__ eperm) {
    int e = blockIdx.x * 256 + threadIdx.x;
    if (e < NE) {
        int d = ei[NE + e];
        int pos = partial[d] + bsum[d >> 10] + atomicAdd(&cursor[d], 1);
        eperm[pos] = e;
    }
}

// ---------------- message MLP: lane-direct gather + segmented aggregation ----------------
// 64 dst-sorted edges per block, 4 waves. launch_bounds(256,4) = 128-VGPR cap
// (no spill risk around hidden-asm MFMAs); if the compiler lands at <=64 VGPR
// (as in round 4), the 17.7 KB LDS allows 8 blocks/CU at runtime.
__global__ __launch_bounds__(256, 4)
void msg_kernel(const float* __restrict__ x, const int* __restrict__ ei,
                const float* __restrict__ ea, const float* __restrict__ cd,
                const int* __restrict__ eperm,
                const unsigned short* __restrict__ W1p, const float* __restrict__ mb1,
                const unsigned short* __restrict__ W2p, const float* __restrict__ mb2,
                float* __restrict__ aggr) {
    __shared__ unsigned short sH[64 * 136];   // hidden tile, then bf16 out tile
    __shared__ int sDst[64];

    const int tid = threadIdx.x;
    const int lane = tid & 63;
    const int wid = tid >> 6;
    const int g = lane >> 4;
    const int lr = lane & 15;
    const int arow = wid * 16 + lr;          // this lane's edge row in the 64-tile
    const int e0 = blockIdx.x * 64;

    const int eid = eperm[e0 + arow];
    const int src = ei[eid];
    const int dst = ei[NE + eid];
    if (g == 0) sDst[arow] = dst;

    // 18 independent gathers straight into fragment slices.
    const float* xs = x + (size_t)src * 128 + g * 8;
    const float* xd = x + (size_t)dst * 128 + g * 8;
    const float* ep = ea + (size_t)eid * 32 + g * 8;
    float4 ts[8], td[8], te[2];
    #pragma unroll
    for (int kk = 0; kk < 4; ++kk) {
        ts[2 * kk]     = *reinterpret_cast<const float4*>(xs + kk * 32);
        ts[2 * kk + 1] = *reinterpret_cast<const float4*>(xs + kk * 32 + 4);
        td[2 * kk]     = *reinterpret_cast<const float4*>(xd + kk * 32);
        td[2 * kk + 1] = *reinterpret_cast<const float4*>(xd + kk * 32 + 4);
    }
    te[0] = *reinterpret_cast<const float4*>(ep);
    te[1] = *reinterpret_cast<const float4*>(ep + 4);
    float rel0 = 0.0f, rel1 = 0.0f, rel2 = 0.0f;
    if (g == 0) {
        rel0 = cd[dst * 3 + 0] - cd[src * 3 + 0];
        rel1 = cd[dst * 3 + 1] - cd[src * 3 + 1];
        rel2 = cd[dst * 3 + 2] - cd[src * 3 + 2];
    }

    short8 af[10];
    #pragma unroll
    for (int kk = 0; kk < 4; ++kk) {
        af[kk]     = pack2(ts[2 * kk], ts[2 * kk + 1]);
        af[4 + kk] = pack2(td[2 * kk], td[2 * kk + 1]);
    }
    af[8] = pack2(te[0], te[1]);
    {   // k 288..319: rel for g==0 j<3; zeros elsewhere (k>=291 weights are zero-padded)
        float4 r0; r0.x = rel0; r0.y = rel1; r0.z = rel2; r0.w = 0.0f;
        float4 r1; r1.x = 0.0f; r1.y = 0.0f; r1.z = 0.0f; r1.w = 0.0f;
        af[9] = pack2(r0, r1);
    }

    // Layer 1: (64x320) @ (320x128)
    floatx4 acc[8];
    #pragma unroll
    for (int n = 0; n < 8; ++n)
        #pragma unroll
        for (int r = 0; r < 4; ++r) acc[n][r] = 0.0f;
    NOPGUARD_INIT8(acc);

    #pragma unroll
    for (int kk = 0; kk < 10; ++kk) {
        const short8* wb = reinterpret_cast<const short8*>(W1p) + (kk * 8) * 64 + lane;
        #pragma unroll
        for (int n = 0; n < 8; ++n)
            acc[n] = mfma16x16x32(af[kk], wb[n * 64], acc[n]);
    }
    NOPGUARD8(acc);

    // bias + ReLU -> sH (bf16)
    #pragma unroll
    for (int n = 0; n < 8; ++n) {
        float bias = mb1[n * 16 + lr];
        #pragma unroll
        for (int r = 0; r < 4; ++r) {
            int row = wid * 16 + g * 4 + r;
            sH[row * 136 + n * 16 + lr] = f2bf(fmaxf(acc[n][r] + bias, 0.0f));
        }
    }
    __syncthreads();

    // Pull layer-2 A fragments to registers, then the buffer is free for reuse.
    short8 a2[4];
    #pragma unroll
    for (int kk = 0; kk < 4; ++kk)
        a2[kk] = *reinterpret_cast<const short8*>(&sH[arow * 136 + kk * 32 + g * 8]);
    __syncthreads();

    // Layer 2: (64x128) @ (128x128)
    floatx4 acc2[8];
    #pragma unroll
    for (int n = 0; n < 8; ++n)
        #pragma unroll
        for (int r = 0; r < 4; ++r) acc2[n][r] = 0.0f;
    NOPGUARD_INIT8(acc2);

    #pragma unroll
    for (int kk = 0; kk < 4; ++kk) {
        const short8* wb = reinterpret_cast<const short8*>(W2p) + (kk * 8) * 64 + lane;
        #pragma unroll
        for (int n = 0; n < 8; ++n)
            acc2[n] = mfma16x16x32(a2[kk], wb[n * 64], acc2[n]);
    }
    NOPGUARD8(acc2);

    // bias -> bf16 LDS out tile (same buffer as hidden tile)
    #pragma unroll
    for (int n = 0; n < 8; ++n) {
        float bias = mb2[n * 16 + lr];
        #pragma unroll
        for (int r = 0; r < 4; ++r) {
            int row = wid * 16 + g * 4 + r;
            sH[row * 136 + n * 16 + lr] = f2bf(acc2[n][r] + bias);
        }
    }
    __syncthreads();

    // Segmented reduction over dst-sorted rows: one atomic row per distinct dst.
    {
        int col = tid & 127;
        int half = tid >> 7;
        int row = 0, s = 0;
        while (row < 64) {
            int d = sDst[row];
            int row2 = row + 1;
            while (row2 < 64 && sDst[row2] == d) ++row2;
            if ((s & 1) == half) {
                float sum = 0.0f;
                for (int r = row; r < row2; ++r) {
                    unsigned int uu = sH[r * 136 + col];
                    sum += __uint_as_float(uu << 16);
                }
                atomicAdd(&aggr[d * 128 + col], sum);
            }
            row = row2; ++s;
        }
    }
}

// ---------------- node update MLP + residual + LayerNorm ----------------
// Lane-direct fragment loads; launch_bounds(256,4) -> 128-VGPR cap, no spills.
__global__ __launch_bounds__(256, 4)
void node_kernel(const float* __restrict__ x, const float* __restrict__ aggr,
                 const unsigned short* __restrict__ U1p, const float* __restrict__ ub1,
                 const unsigned short* __restrict__ U2p, const float* __restrict__ ub2,
                 const float* __restrict__ gamma, const float* __restrict__ beta,
                 float* __restrict__ out) {
    __shared__ unsigned short sH[64 * 136];

    const int tid = threadIdx.x;
    const int lane = tid & 63;
    const int wid = tid >> 6;
    const int g = lane >> 4;
    const int lr = lane & 15;
    const int arow = wid * 16 + lr;
    const int n0 = blockIdx.x * 64;

    int nd0 = n0 + arow;
    int ndc0 = (nd0 < NN) ? nd0 : (NN - 1);

    const float* xp = x + (size_t)ndc0 * 128 + g * 8;
    const float* ap = aggr + (size_t)ndc0 * 128 + g * 8;
    float4 tx[8], ta[8];
    #pragma unroll
    for (int kk = 0; kk < 4; ++kk) {
        tx[2 * kk]     = *reinterpret_cast<const float4*>(xp + kk * 32);
        tx[2 * kk + 1] = *reinterpret_cast<const float4*>(xp + kk * 32 + 4);
        ta[2 * kk]     = *reinterpret_cast<const float4*>(ap + kk * 32);
        ta[2 * kk + 1] = *reinterpret_cast<const float4*>(ap + kk * 32 + 4);
    }

    short8 af[8];
    #pragma unroll
    for (int kk = 0; kk < 4; ++kk) {
        af[kk]     = pack2(tx[2 * kk], tx[2 * kk + 1]);
        af[4 + kk] = pack2(ta[2 * kk], ta[2 * kk + 1]);
    }

    // Layer 1: (64x256) @ (256x128)
    floatx4 acc[8];
    #pragma unroll
    for (int n = 0; n < 8; ++n)
        #pragma unroll
        for (int r = 0; r < 4; ++r) acc[n][r] = 0.0f;
    NOPGUARD_INIT8(acc);

    #pragma unroll
    for (int kk = 0; kk < 8; ++kk) {
        const short8* wb = reinterpret_cast<const short8*>(U1p) + (kk * 8) * 64 + lane;
        #pragma unroll
        for (int n = 0; n < 8; ++n)
            acc[n] = mfma16x16x32(af[kk], wb[n * 64], acc[n]);
    }
    NOPGUARD8(acc);

    #pragma unroll
    for (int n = 0; n < 8; ++n) {
        float bias = ub1[n * 16 + lr];
        #pragma unroll
        for (int r = 0; r < 4; ++r) {
            int row = wid * 16 + g * 4 + r;
            sH[row * 136 + n * 16 + lr] = f2bf(fmaxf(acc[n][r] + bias, 0.0f));
        }
    }
    __syncthreads();

    short8 a2[4];
    #pragma unroll
    for (int kk = 0; kk < 4; ++kk)
        a2[kk] = *reinterpret_cast<const short8*>(&sH[arow * 136 + kk * 32 + g * 8]);

    // Layer 2: (64x128) @ (128x128)
    floatx4 acc2[8];
    #pragma unroll
    for (int n = 0; n < 8; ++n)
        #pragma unroll
        for (int r = 0; r < 4; ++r) acc2[n][r] = 0.0f;
    NOPGUARD_INIT8(acc2);

    #pragma unroll
    for (int kk = 0; kk < 4; ++kk) {
        const short8* wb = reinterpret_cast<const short8*>(U2p) + (kk * 8) * 64 + lane;
        #pragma unroll
        for (int n = 0; n < 8; ++n)
            acc2[n] = mfma16x16x32(a2[kk], wb[n * 64], acc2[n]);
    }
    NOPGUARD8(acc2);

    // Epilogue: residual + LayerNorm in registers (16-lane shfl_xor row-reduce).
    #pragma unroll
    for (int r = 0; r < 4; ++r) {
        int row = wid * 16 + g * 4 + r;
        int nd = n0 + row;
        int ndc = (nd < NN) ? nd : (NN - 1);
        float vals[8];
        float s1 = 0.0f, s2 = 0.0f;
        #pragma unroll
        for (int n = 0; n < 8; ++n) {
            int col = n * 16 + lr;
            float v = acc2[n][r] + ub2[col] + x[ndc * 128 + col];
            vals[n] = v;
            s1 += v;
            s2 += v * v;
        }
        #pragma unroll
        for (int m = 1; m < 16; m <<= 1) {
            s1 += __shfl_xor(s1, m);
            s2 += __shfl_xor(s2, m);
        }
        float mean = s1 * (1.0f / 128.0f);
        float var = s2 * (1.0f / 128.0f) - mean * mean;
        float inv = rsqrtf(var + 1e-5f);
        if (nd < NN) {
            #pragma unroll
            for (int n = 0; n < 8; ++n) {
                int col = n * 16 + lr;
                out[nd * 128 + col] = (vals[n] - mean) * inv * gamma[col] + beta[col];
            }
        }
    }
}

extern "C" void kernel_launch(void* const* d_in, const int* in_sizes, int n_in,
                              void* d_out, int out_size, void* d_ws, size_t ws_size,
                              hipStream_t stream) {
    const float* x     = (const float*)d_in[0];
    const int*   ei    = (const int*)d_in[1];
    const float* ea    = (const float*)d_in[2];
    const float* cd    = (const float*)d_in[3];
    const float* mW1   = (const float*)d_in[4];
    const float* mb1   = (const float*)d_in[5];
    const float* mW2   = (const float*)d_in[6];
    const float* mb2   = (const float*)d_in[7];
    const float* uW1   = (const float*)d_in[8];
    const float* ub1   = (const float*)d_in[9];
    const float* uW2   = (const float*)d_in[10];
    const float* ub2   = (const float*)d_in[11];
    const float* gamma = (const float*)d_in[12];
    const float* beta  = (const float*)d_in[13];
    float* out = (float*)d_out;

    char* ws = (char*)d_ws;
    unsigned short* W1p = (unsigned short*)(ws);              // 81,920 B
    unsigned short* W2p = (unsigned short*)(ws + 81920);      // 32,768 B
    unsigned short* U1p = (unsigned short*)(ws + 114688);     // 65,536 B
    unsigned short* U2p = (unsigned short*)(ws + 180224);     // 32,768 B
    int* counts  = (int*)(ws + 212992);                       // 200,704 B
    int* partial = (int*)(ws + 413696);                       // 200,704 B
    int* bsum    = (int*)(ws + 614400);                       // 256 B
    int* cursor  = (int*)(ws + 614656);                       // 200,704 B
    int* eperm   = (int*)(ws + 815360);                       // 3,200,000 B

    float* aggr = out;   // aggr lives in d_out (exactly NN*HD floats)

    hipMemsetAsync(counts, 0, NN * sizeof(int), stream);
    hipMemsetAsync(cursor, 0, NN * sizeof(int), stream);
    hipMemsetAsync(aggr, 0, (size_t)NN * HD * sizeof(float), stream);

    pack_weights<<<416, 256, 0, stream>>>(mW1, mW2, uW1, uW2, W1p, W2p, U1p, U2p);
    hist_kernel<<<(NE + 255) / 256, 256, 0, stream>>>(ei, counts);
    scan1_kernel<<<(NN + 1023) / 1024, 1024, 0, stream>>>(counts, partial, bsum);
    scan2_kernel<<<1, 64, 0, stream>>>(bsum, (NN + 1023) / 1024);
    scatter_kernel<<<(NE + 255) / 256, 256, 0, stream>>>(ei, partial, bsum, cursor, eperm);
    msg_kernel<<<NE / 64, 256, 0, stream>>>(x, ei, ea, cd, eperm, W1p, mb1, W2p, mb2, aggr);
    node_kernel<<<(NN + 63) / 64, 256, 0, stream>>>(x, aggr, U1p, ub1, U2p, ub2, gamma, beta, out);
}